// Round 6
// baseline (1241.114 us; speedup 1.0000x reference)
//
#include <hip/hip_runtime.h>

#define NN 100000
#define CC 128
#define EE 1600000
#define GG 1024
#define LL 5
#define NB_BUCKET ((NN + 127) / 128)   // 782

typedef __attribute__((ext_vector_type(8))) short bf16x8;
typedef __attribute__((ext_vector_type(4))) float f32x4;

__device__ __forceinline__ float sigmoidf_(float x) { return 1.0f / (1.0f + __expf(-x)); }
__device__ __forceinline__ float tanhf_(float x) {
  float xx = fminf(15.0f, fmaxf(-15.0f, x));
  float t = __expf(-2.0f * xx);
  return (1.0f - t) / (1.0f + t);
}
// f32 -> bf16 round-to-nearest-even
__device__ __forceinline__ unsigned short f2bf(float x) {
  unsigned int u = __float_as_uint(x);
  return (unsigned short)((u + 0x7fffu + ((u >> 16) & 1u)) >> 16);
}
__device__ __forceinline__ float bflo(unsigned int u) { return __uint_as_float(u << 16); }
__device__ __forceinline__ float bfhi(unsigned int u) { return __uint_as_float(u & 0xffff0000u); }

// ---------------- weight prepack ----------------
// Packed B-fragment layout: element (k, c) at t = ((cb*4+ks)*64 + l)*8 + i
// with k = ks*32 + 8*(l>>4) + i, c = cb*16 + (l&15).

// Whh: B[k][c] = W_hh[c][k]  (gh = h @ W_hh^T)
__global__ __launch_bounds__(256) void pack_kernel(
    const float* __restrict__ src, unsigned short* __restrict__ dst)
{
  int t = blockIdx.x * 256 + threadIdx.x;           // 24*4*64*8 = 49152
  int i = t & 7, l = (t >> 3) & 63, q = t >> 9;
  int ks = q & 3, cb = q >> 2;
  int k = ks * 32 + 8 * (l >> 4) + i;
  int c = cb * 16 + (l & 15);
  dst[t] = f2bf(src[(size_t)c * CC + k]);
}

// Wfuse_l[k][c] = sum_j W_l[k][j] * W_ih[c][j]   (gi = aggP @ Wfuse)
__global__ __launch_bounds__(256) void fuse_pack_kernel(
    const float* __restrict__ Wl, const float* __restrict__ W_ih,
    unsigned short* __restrict__ dst)
{
  int t = blockIdx.x * 256 + threadIdx.x;           // 49152 per layer
  int i = t & 7, l = (t >> 3) & 63, q = t >> 9;
  int ks = q & 3, cb = q >> 2;
  int k = ks * 32 + 8 * (l >> 4) + i;
  int c = cb * 16 + (l & 15);
  const float* wl = Wl + (size_t)k * CC;
  const float* wi = W_ih + (size_t)c * CC;
  float acc = 0.f;
  #pragma unroll 8
  for (int j = 0; j < CC; ++j) acc = fmaf(wl[j], wi[j], acc);
  dst[t] = f2bf(acc);
}

// ---------------- CSR build (once per call) ----------------

__global__ __launch_bounds__(256) void hist_kernel(const int* __restrict__ eidx,
                                                   int* __restrict__ deg)
{
  int e = blockIdx.x * blockDim.x + threadIdx.x;
  if (e < EE) atomicAdd(&deg[eidx[EE + e]], 1);
}

__global__ __launch_bounds__(256) void scan1_kernel(const int* __restrict__ deg,
                                                    int* __restrict__ bsum)
{
  __shared__ int red[4];
  int base = blockIdx.x * 1024 + threadIdx.x * 4;
  int s = 0;
  #pragma unroll
  for (int i = 0; i < 4; ++i) { int idx = base + i; if (idx < NN) s += deg[idx]; }
  #pragma unroll
  for (int off = 32; off; off >>= 1) s += __shfl_down(s, off, 64);
  if ((threadIdx.x & 63) == 0) red[threadIdx.x >> 6] = s;
  __syncthreads();
  if (threadIdx.x == 0) bsum[blockIdx.x] = red[0] + red[1] + red[2] + red[3];
}

__global__ void scan2_kernel(int* __restrict__ bsum, int nb)
{
  if (threadIdx.x == 0 && blockIdx.x == 0) {
    int acc = 0;
    for (int i = 0; i < nb; ++i) { int v = bsum[i]; bsum[i] = acc; acc += v; }
  }
}

__global__ __launch_bounds__(256) void scan3_kernel(const int* __restrict__ deg,
                                                    const int* __restrict__ bsum,
                                                    int* __restrict__ row_ptr)
{
  __shared__ int ts[256];
  const int tid = threadIdx.x;
  const int base = blockIdx.x * 1024 + tid * 4;
  int v[4]; int s = 0;
  #pragma unroll
  for (int i = 0; i < 4; ++i) { int idx = base + i; v[i] = (idx < NN) ? deg[idx] : 0; s += v[i]; }
  ts[tid] = s; __syncthreads();
  for (int off = 1; off < 256; off <<= 1) {
    int t = (tid >= off) ? ts[tid - off] : 0;
    __syncthreads();
    ts[tid] += t;
    __syncthreads();
  }
  int excl = bsum[blockIdx.x] + ts[tid] - s;
  #pragma unroll
  for (int i = 0; i < 4; ++i) {
    int idx = base + i;
    if (idx < NN) { row_ptr[idx] = excl; excl += v[i]; }
  }
  if (blockIdx.x == 0 && tid == 0) row_ptr[NN] = EE;
}

// bucket cursors: bucket b (dst in [128b,128b+128)) owns CSR span starting row_ptr[128b]
__global__ void bcur_init_kernel(const int* __restrict__ row_ptr, int* __restrict__ bcur)
{
  int b = blockIdx.x * blockDim.x + threadIdx.x;
  if (b < NB_BUCKET) bcur[b] = row_ptr[b * 128];
}

// phase 1: append edges into their dst-bucket span (dense writes, ~1x amplification)
__global__ __launch_bounds__(256) void fill_bucket_kernel(
    const int* __restrict__ eidx, const float* __restrict__ ew,
    int* __restrict__ bcur, int2* __restrict__ bucket)
{
  int e = blockIdx.x * blockDim.x + threadIdx.x;
  if (e < EE) {
    int d = eidx[EE + e];
    int p = atomicAdd(&bcur[d >> 7], 1);
    bucket[p] = make_int2(eidx[e] | ((d & 127) << 17), __float_as_int(ew[e]));
  }
}

// phase 2: one block per bucket; LDS cursors; scattered stores confined to ~16KB span
__global__ __launch_bounds__(256) void fill_csr_kernel(
    const int* __restrict__ row_ptr, const int2* __restrict__ bucket,
    int2* __restrict__ csr_sw)
{
  __shared__ int cur[128];
  const int b = blockIdx.x;
  const int base_node = b * 128;
  const int tid = threadIdx.x;
  if (tid < 128) {
    int nidx = base_node + tid;
    cur[tid] = (nidx < NN) ? row_ptr[nidx] : 0;
  }
  __syncthreads();
  const int start = row_ptr[base_node];
  const int stop  = row_ptr[min(base_node + 128, NN)];
  for (int j = start + tid; j < stop; j += 256) {
    int2 r = bucket[j];
    unsigned u = (unsigned)r.x;
    int src  = (int)(u & 0x1FFFFu);
    int dlow = (int)(u >> 17);
    int p = atomicAdd(&cur[dlow], 1);
    csr_sw[p] = make_int2(src, r.y);
  }
}

// ---------------- main pipeline ----------------

// h0 = x @ W_emb + b_emb; writes f32 h and bf16 mirror
__global__ __launch_bounds__(128) void embed_kernel(
    const float* __restrict__ x, const float* __restrict__ W_emb,
    const float* __restrict__ b_emb, float* __restrict__ h,
    unsigned short* __restrict__ h_bf)
{
  const int node = blockIdx.x;
  const int c = threadIdx.x;
  float acc = b_emb[c];
  #pragma unroll
  for (int k = 0; k < 32; ++k)
    acc = fmaf(x[node * 32 + k], W_emb[k * CC + c], acc);
  h[(size_t)node * CC + c] = acc;
  h_bf[(size_t)node * CC + c] = f2bf(acc);
}

// agg_bf[n] = bf16( sum_{e:dst=n} h_bf[src_e] * w_e ) — CSR gather.
// 4 quarters x 16 lanes; 16 edges in flight (typical node = ONE iteration).
__global__ __launch_bounds__(256) void aggregate_kernel(
    const unsigned short* __restrict__ h_bf, const int* __restrict__ row_ptr,
    const int2* __restrict__ csr_sw, unsigned short* __restrict__ agg_bf)
{
  const int lane = threadIdx.x & 63;
  const int node = (blockIdx.x * blockDim.x + threadIdx.x) >> 6;
  if (node >= NN) return;
  const int q = lane >> 4;          // quarter 0..3
  const int t = lane & 15;          // lane within quarter
  const int beg = row_ptr[node], end = row_ptr[node + 1];

  float acc[8] = {0.f, 0.f, 0.f, 0.f, 0.f, 0.f, 0.f, 0.f};
  const int last = end - 1;

  for (int j = beg; j < end; j += 16) {
    const int e0 = j + q, e1 = j + 4 + q, e2 = j + 8 + q, e3 = j + 12 + q;
    const int i0 = min(e0, last), i1 = min(e1, last);
    const int i2 = min(e2, last), i3 = min(e3, last);
    const int2 r0 = csr_sw[i0], r1 = csr_sw[i1], r2 = csr_sw[i2], r3 = csr_sw[i3];
    const float w0 = (e0 < end) ? __int_as_float(r0.y) : 0.0f;
    const float w1 = (e1 < end) ? __int_as_float(r1.y) : 0.0f;
    const float w2 = (e2 < end) ? __int_as_float(r2.y) : 0.0f;
    const float w3 = (e3 < end) ? __int_as_float(r3.y) : 0.0f;
    const uint4 u0 = *(const uint4*)(h_bf + (size_t)r0.x * CC + t * 8);
    const uint4 u1 = *(const uint4*)(h_bf + (size_t)r1.x * CC + t * 8);
    const uint4 u2 = *(const uint4*)(h_bf + (size_t)r2.x * CC + t * 8);
    const uint4 u3 = *(const uint4*)(h_bf + (size_t)r3.x * CC + t * 8);
    acc[0] = fmaf(bflo(u0.x), w0, acc[0]); acc[1] = fmaf(bfhi(u0.x), w0, acc[1]);
    acc[2] = fmaf(bflo(u0.y), w0, acc[2]); acc[3] = fmaf(bfhi(u0.y), w0, acc[3]);
    acc[4] = fmaf(bflo(u0.z), w0, acc[4]); acc[5] = fmaf(bfhi(u0.z), w0, acc[5]);
    acc[6] = fmaf(bflo(u0.w), w0, acc[6]); acc[7] = fmaf(bfhi(u0.w), w0, acc[7]);
    acc[0] = fmaf(bflo(u1.x), w1, acc[0]); acc[1] = fmaf(bfhi(u1.x), w1, acc[1]);
    acc[2] = fmaf(bflo(u1.y), w1, acc[2]); acc[3] = fmaf(bfhi(u1.y), w1, acc[3]);
    acc[4] = fmaf(bflo(u1.z), w1, acc[4]); acc[5] = fmaf(bfhi(u1.z), w1, acc[5]);
    acc[6] = fmaf(bflo(u1.w), w1, acc[6]); acc[7] = fmaf(bfhi(u1.w), w1, acc[7]);
    acc[0] = fmaf(bflo(u2.x), w2, acc[0]); acc[1] = fmaf(bfhi(u2.x), w2, acc[1]);
    acc[2] = fmaf(bflo(u2.y), w2, acc[2]); acc[3] = fmaf(bfhi(u2.y), w2, acc[3]);
    acc[4] = fmaf(bflo(u2.z), w2, acc[4]); acc[5] = fmaf(bfhi(u2.z), w2, acc[5]);
    acc[6] = fmaf(bflo(u2.w), w2, acc[6]); acc[7] = fmaf(bfhi(u2.w), w2, acc[7]);
    acc[0] = fmaf(bflo(u3.x), w3, acc[0]); acc[1] = fmaf(bfhi(u3.x), w3, acc[1]);
    acc[2] = fmaf(bflo(u3.y), w3, acc[2]); acc[3] = fmaf(bfhi(u3.y), w3, acc[3]);
    acc[4] = fmaf(bflo(u3.z), w3, acc[4]); acc[5] = fmaf(bfhi(u3.z), w3, acc[5]);
    acc[6] = fmaf(bflo(u3.w), w3, acc[6]); acc[7] = fmaf(bfhi(u3.w), w3, acc[7]);
  }

  #pragma unroll
  for (int i = 0; i < 8; ++i) {
    acc[i] += __shfl_xor(acc[i], 16, 64);
    acc[i] += __shfl_xor(acc[i], 32, 64);
  }

  if (q == 0) {
    uint4 o;
    o.x = (unsigned)f2bf(acc[0]) | ((unsigned)f2bf(acc[1]) << 16);
    o.y = (unsigned)f2bf(acc[2]) | ((unsigned)f2bf(acc[3]) << 16);
    o.z = (unsigned)f2bf(acc[4]) | ((unsigned)f2bf(acc[5]) << 16);
    o.w = (unsigned)f2bf(acc[6]) | ((unsigned)f2bf(acc[7]) << 16);
    *(uint4*)(agg_bf + (size_t)node * CC + t * 8) = o;
  }
}

// fused GRU via MFMA: h = GRU(aggP @ Wfuse, h).
// Wave handles 32 nodes (two 16-row M-tiles sharing every B-fragment);
// per col-block cb all three gates are computed, fused, blended, stored.
__global__ __launch_bounds__(256) void gru_kernel(
    const unsigned short* __restrict__ agg_bf, float* __restrict__ h,
    unsigned short* __restrict__ h_bf,
    const unsigned short* __restrict__ Wfuse_p, const unsigned short* __restrict__ Whh_p,
    const float* __restrict__ b_ih, const float* __restrict__ b_hh)
{
  const int lane = threadIdx.x & 63;
  const int wave = threadIdx.x >> 6;
  const int node0 = blockIdx.x * 128 + wave * 32;
  if (node0 >= NN) return;
  const int col16 = lane & 15, grp = lane >> 4;

  bf16x8 aA[2][4], aH[2][4];
  #pragma unroll
  for (int t = 0; t < 2; ++t) {
    const unsigned short* arow = agg_bf + (size_t)(node0 + t * 16 + col16) * CC + grp * 8;
    const unsigned short* hrow = h_bf  + (size_t)(node0 + t * 16 + col16) * CC + grp * 8;
    #pragma unroll
    for (int ks = 0; ks < 4; ++ks) {
      aA[t][ks] = *(const bf16x8*)(arow + ks * 32);
      aH[t][ks] = *(const bf16x8*)(hrow + ks * 32);
    }
  }

  const f32x4 z4 = {0.f, 0.f, 0.f, 0.f};

  #pragma unroll
  for (int cb = 0; cb < 8; ++cb) {
    f32x4 air[2] = {z4, z4}, ahr[2] = {z4, z4};
    f32x4 aiz[2] = {z4, z4}, ahz[2] = {z4, z4};
    f32x4 ain[2] = {z4, z4}, ahn[2] = {z4, z4};
    #pragma unroll
    for (int ks = 0; ks < 4; ++ks) {
      const size_t or_ = (size_t)((cb * 4 + ks) * 64 + lane) * 8;
      const size_t oz_ = (size_t)(((8 + cb) * 4 + ks) * 64 + lane) * 8;
      const size_t on_ = (size_t)(((16 + cb) * 4 + ks) * 64 + lane) * 8;
      bf16x8 bir = *(const bf16x8*)(Wfuse_p + or_);
      bf16x8 bhr = *(const bf16x8*)(Whh_p + or_);
      bf16x8 biz = *(const bf16x8*)(Wfuse_p + oz_);
      bf16x8 bhz = *(const bf16x8*)(Whh_p + oz_);
      bf16x8 bin = *(const bf16x8*)(Wfuse_p + on_);
      bf16x8 bhn = *(const bf16x8*)(Whh_p + on_);
      #pragma unroll
      for (int t = 0; t < 2; ++t) {
        air[t] = __builtin_amdgcn_mfma_f32_16x16x32_bf16(aA[t][ks], bir, air[t], 0, 0, 0);
        ahr[t] = __builtin_amdgcn_mfma_f32_16x16x32_bf16(aH[t][ks], bhr, ahr[t], 0, 0, 0);
        aiz[t] = __builtin_amdgcn_mfma_f32_16x16x32_bf16(aA[t][ks], biz, aiz[t], 0, 0, 0);
        ahz[t] = __builtin_amdgcn_mfma_f32_16x16x32_bf16(aH[t][ks], bhz, ahz[t], 0, 0, 0);
        ain[t] = __builtin_amdgcn_mfma_f32_16x16x32_bf16(aA[t][ks], bin, ain[t], 0, 0, 0);
        ahn[t] = __builtin_amdgcn_mfma_f32_16x16x32_bf16(aH[t][ks], bhn, ahn[t], 0, 0, 0);
      }
    }
    const int o = cb * 16 + col16;
    const float bir_ = b_ih[o],       bhr_ = b_hh[o];
    const float biz_ = b_ih[128 + o], bhz_ = b_hh[128 + o];
    const float bin_ = b_ih[256 + o], bhn_ = b_hh[256 + o];
    #pragma unroll
    for (int t = 0; t < 2; ++t) {
      #pragma unroll
      for (int r = 0; r < 4; ++r) {
        float rr = sigmoidf_(air[t][r] + ahr[t][r] + bir_ + bhr_);
        float zz = sigmoidf_(aiz[t][r] + ahz[t][r] + biz_ + bhz_);
        float nn = tanhf_(ain[t][r] + bin_ + rr * (ahn[t][r] + bhn_));
        size_t idx = (size_t)(node0 + t * 16 + grp * 4 + r) * CC + o;
        float hn = (1.0f - zz) * nn + zz * h[idx];
        h[idx] = hn;
        h_bf[idx] = f2bf(hn);
      }
    }
  }
}

// out[batch[n]] += h[n] . W_prop + b_prop   (wave per node)
__global__ __launch_bounds__(256) void prop_kernel(
    const float* __restrict__ h, const int* __restrict__ batch,
    const float* __restrict__ Wp, const float* __restrict__ bp,
    float* __restrict__ out)
{
  const int lane = threadIdx.x & 63;
  const int wid = (blockIdx.x * blockDim.x + threadIdx.x) >> 6;
  const int nw = (gridDim.x * blockDim.x) >> 6;
  for (int node = wid; node < NN; node += nw) {
    float v = h[(size_t)node * CC + lane] * Wp[lane]
            + h[(size_t)node * CC + 64 + lane] * Wp[64 + lane];
    #pragma unroll
    for (int off = 32; off > 0; off >>= 1) v += __shfl_down(v, off, 64);
    if (lane == 0) atomicAdd(&out[batch[node]], v + bp[0]);
  }
}

extern "C" void kernel_launch(void* const* d_in, const int* in_sizes, int n_in,
                              void* d_out, int out_size, void* d_ws, size_t ws_size,
                              hipStream_t stream)
{
  const float* x      = (const float*)d_in[0];
  const int*   eidx   = (const int*)d_in[1];
  const float* ew     = (const float*)d_in[2];
  const int*   batch  = (const int*)d_in[3];
  const float* W_emb  = (const float*)d_in[4];
  const float* b_emb  = (const float*)d_in[5];
  const float* W      = (const float*)d_in[6];
  const float* W_ih   = (const float*)d_in[7];
  const float* W_hh   = (const float*)d_in[8];
  const float* b_ih   = (const float*)d_in[9];
  const float* b_hh   = (const float*)d_in[10];
  const float* W_prop = (const float*)d_in[11];
  const float* b_prop = (const float*)d_in[12];
  float* out = (float*)d_out;

  // workspace layout (~129 MB)
  char* p = (char*)d_ws;
  float* h              = (float*)p;          p += (size_t)NN * CC * sizeof(float);  // 51.2 MB
  unsigned short* h_bf  = (unsigned short*)p; p += (size_t)NN * CC * sizeof(short);  // 25.6 MB
  unsigned short* agg   = (unsigned short*)p; p += (size_t)NN * CC * sizeof(short);  // 25.6 MB
  int2* csr_sw          = (int2*)p;           p += (size_t)EE * sizeof(int2);        // 12.8 MB
  int2* bucket          = (int2*)p;           p += (size_t)EE * sizeof(int2);        // 12.8 MB
  unsigned short* Wfuse_p = (unsigned short*)p; p += (size_t)LL * 49152 * sizeof(short);
  unsigned short* Whh_p = (unsigned short*)p; p += (size_t)49152 * sizeof(short);
  int* deg     = (int*)p;                     p += (size_t)(NN + 256) * sizeof(int);
  int* row_ptr = (int*)p;                     p += (size_t)(NN + 256) * sizeof(int);
  int* bcur    = (int*)p;                     p += (size_t)(NB_BUCKET + 64) * sizeof(int);
  int* bsum    = (int*)p;                     p += 1024 * sizeof(int);

  const int NB_SCAN = (NN + 1023) / 1024;   // 98
  const int EB = (EE + 255) / 256;          // 6250
  const int MB2 = (NN + 127) / 128;         // 782 (gru: 128 nodes/block)

  // ---- weight prepack (once per call) ----
  pack_kernel<<<192, 256, 0, stream>>>(W_hh, Whh_p);
  for (int l = 0; l < LL; ++l)
    fuse_pack_kernel<<<192, 256, 0, stream>>>(W + (size_t)l * CC * CC, W_ih,
                                              Wfuse_p + (size_t)l * 49152);

  // ---- CSR build: hist -> scan -> bucket scatter -> per-bucket CSR ----
  hipMemsetAsync(deg, 0, (size_t)NN * sizeof(int), stream);
  hist_kernel<<<EB, 256, 0, stream>>>(eidx, deg);
  scan1_kernel<<<NB_SCAN, 256, 0, stream>>>(deg, bsum);
  scan2_kernel<<<1, 64, 0, stream>>>(bsum, NB_SCAN);
  scan3_kernel<<<NB_SCAN, 256, 0, stream>>>(deg, bsum, row_ptr);
  bcur_init_kernel<<<(NB_BUCKET + 255) / 256, 256, 0, stream>>>(row_ptr, bcur);
  fill_bucket_kernel<<<EB, 256, 0, stream>>>(eidx, ew, bcur, bucket);
  fill_csr_kernel<<<NB_BUCKET, 256, 0, stream>>>(row_ptr, bucket, csr_sw);

  // ---- main pipeline ----
  embed_kernel<<<NN, 128, 0, stream>>>(x, W_emb, b_emb, h, h_bf);

  for (int l = 0; l < LL; ++l) {
    aggregate_kernel<<<(NN + 3) / 4, 256, 0, stream>>>(h_bf, row_ptr, csr_sw, agg);
    gru_kernel<<<MB2, 256, 0, stream>>>(agg, h, h_bf,
                                        Wfuse_p + (size_t)l * 49152, Whh_p, b_ih, b_hh);
  }

  hipMemsetAsync(d_out, 0, (size_t)GG * sizeof(float), stream);
  prop_kernel<<<2048, 256, 0, stream>>>(h, batch, W_prop, b_prop, out);
}

// Round 7
// 947.398 us; speedup vs baseline: 1.3100x; 1.3100x over previous
//
#include <hip/hip_runtime.h>

#define NN 100000
#define CC 128
#define EE 1600000
#define GG 1024
#define LL 5

typedef __attribute__((ext_vector_type(8))) short bf16x8;
typedef __attribute__((ext_vector_type(4))) float f32x4;

__device__ __forceinline__ float sigmoidf_(float x) { return 1.0f / (1.0f + __expf(-x)); }
__device__ __forceinline__ float tanhf_(float x) {
  float xx = fminf(15.0f, fmaxf(-15.0f, x));
  float t = __expf(-2.0f * xx);
  return (1.0f - t) / (1.0f + t);
}
// f32 -> bf16 round-to-nearest-even
__device__ __forceinline__ unsigned short f2bf(float x) {
  unsigned int u = __float_as_uint(x);
  return (unsigned short)((u + 0x7fffu + ((u >> 16) & 1u)) >> 16);
}
__device__ __forceinline__ float bflo(unsigned int u) { return __uint_as_float(u << 16); }
__device__ __forceinline__ float bfhi(unsigned int u) { return __uint_as_float(u & 0xffff0000u); }

// ---------------- weight prepack ----------------
// Packed B-fragment layout: element (k, c) at t = ((cb*4+ks)*64 + l)*8 + i
// with k = ks*32 + 8*(l>>4) + i, c = cb*16 + (l&15).

// Whh: B[k][c] = W_hh[c][k]  (gh = h @ W_hh^T)
__global__ __launch_bounds__(256) void pack_kernel(
    const float* __restrict__ src, unsigned short* __restrict__ dst)
{
  int t = blockIdx.x * 256 + threadIdx.x;           // 24*4*64*8 = 49152
  int i = t & 7, l = (t >> 3) & 63, q = t >> 9;
  int ks = q & 3, cb = q >> 2;
  int k = ks * 32 + 8 * (l >> 4) + i;
  int c = cb * 16 + (l & 15);
  dst[t] = f2bf(src[(size_t)c * CC + k]);
}

// Wfuse_l[k][c] = sum_j W_l[k][j] * W_ih[c][j]   (gi = aggP @ Wfuse)
__global__ __launch_bounds__(256) void fuse_pack_kernel(
    const float* __restrict__ Wl, const float* __restrict__ W_ih,
    unsigned short* __restrict__ dst)
{
  int t = blockIdx.x * 256 + threadIdx.x;           // 49152 per layer
  int i = t & 7, l = (t >> 3) & 63, q = t >> 9;
  int ks = q & 3, cb = q >> 2;
  int k = ks * 32 + 8 * (l >> 4) + i;
  int c = cb * 16 + (l & 15);
  const float* wl = Wl + (size_t)k * CC;
  const float* wi = W_ih + (size_t)c * CC;
  float acc = 0.f;
  #pragma unroll 8
  for (int j = 0; j < CC; ++j) acc = fmaf(wl[j], wi[j], acc);
  dst[t] = f2bf(acc);
}

// ---------------- CSR build (once per call) ----------------

__global__ __launch_bounds__(256) void hist_kernel(const int* __restrict__ eidx,
                                                   int* __restrict__ deg)
{
  int e = blockIdx.x * blockDim.x + threadIdx.x;
  if (e < EE) atomicAdd(&deg[eidx[EE + e]], 1);
}

__global__ __launch_bounds__(256) void scan1_kernel(const int* __restrict__ deg,
                                                    int* __restrict__ bsum)
{
  __shared__ int red[4];
  int base = blockIdx.x * 1024 + threadIdx.x * 4;
  int s = 0;
  #pragma unroll
  for (int i = 0; i < 4; ++i) { int idx = base + i; if (idx < NN) s += deg[idx]; }
  #pragma unroll
  for (int off = 32; off; off >>= 1) s += __shfl_down(s, off, 64);
  if ((threadIdx.x & 63) == 0) red[threadIdx.x >> 6] = s;
  __syncthreads();
  if (threadIdx.x == 0) bsum[blockIdx.x] = red[0] + red[1] + red[2] + red[3];
}

__global__ void scan2_kernel(int* __restrict__ bsum, int nb)
{
  if (threadIdx.x == 0 && blockIdx.x == 0) {
    int acc = 0;
    for (int i = 0; i < nb; ++i) { int v = bsum[i]; bsum[i] = acc; acc += v; }
  }
}

__global__ __launch_bounds__(256) void scan3_kernel(const int* __restrict__ deg,
                                                    const int* __restrict__ bsum,
                                                    int* __restrict__ row_ptr,
                                                    int* __restrict__ cursor)
{
  __shared__ int ts[256];
  const int tid = threadIdx.x;
  const int base = blockIdx.x * 1024 + tid * 4;
  int v[4]; int s = 0;
  #pragma unroll
  for (int i = 0; i < 4; ++i) { int idx = base + i; v[i] = (idx < NN) ? deg[idx] : 0; s += v[i]; }
  ts[tid] = s; __syncthreads();
  for (int off = 1; off < 256; off <<= 1) {
    int t = (tid >= off) ? ts[tid - off] : 0;
    __syncthreads();
    ts[tid] += t;
    __syncthreads();
  }
  int excl = bsum[blockIdx.x] + ts[tid] - s;
  #pragma unroll
  for (int i = 0; i < 4; ++i) {
    int idx = base + i;
    if (idx < NN) { row_ptr[idx] = excl; cursor[idx] = excl; excl += v[i]; }
  }
  if (blockIdx.x == 0 && tid == 0) row_ptr[NN] = EE;
}

// interleaved (src, weight) record: one 8B scattered store per edge.
// 100K cursors -> negligible atomic contention; write amplification accepted.
__global__ __launch_bounds__(256) void fill_kernel(const int* __restrict__ eidx,
                                                   const float* __restrict__ ew,
                                                   int* __restrict__ cursor,
                                                   int2* __restrict__ csr_sw)
{
  int e = blockIdx.x * blockDim.x + threadIdx.x;
  if (e < EE) {
    int d = eidx[EE + e];
    int p = atomicAdd(&cursor[d], 1);
    csr_sw[p] = make_int2(eidx[e], __float_as_int(ew[e]));
  }
}

// ---------------- main pipeline ----------------

// h0 = x @ W_emb + b_emb; writes f32 h and bf16 mirror
__global__ __launch_bounds__(128) void embed_kernel(
    const float* __restrict__ x, const float* __restrict__ W_emb,
    const float* __restrict__ b_emb, float* __restrict__ h,
    unsigned short* __restrict__ h_bf)
{
  const int node = blockIdx.x;
  const int c = threadIdx.x;
  float acc = b_emb[c];
  #pragma unroll
  for (int k = 0; k < 32; ++k)
    acc = fmaf(x[node * 32 + k], W_emb[k * CC + c], acc);
  h[(size_t)node * CC + c] = acc;
  h_bf[(size_t)node * CC + c] = f2bf(acc);
}

// agg_bf[n] = bf16( sum_{e:dst=n} h_bf[src_e] * w_e ) — CSR gather.
// 4 quarters x 16 lanes; 16 edges in flight (typical node = ONE iteration).
__global__ __launch_bounds__(256) void aggregate_kernel(
    const unsigned short* __restrict__ h_bf, const int* __restrict__ row_ptr,
    const int2* __restrict__ csr_sw, unsigned short* __restrict__ agg_bf)
{
  const int lane = threadIdx.x & 63;
  const int node = (blockIdx.x * blockDim.x + threadIdx.x) >> 6;
  if (node >= NN) return;
  const int q = lane >> 4;          // quarter 0..3
  const int t = lane & 15;          // lane within quarter
  const int beg = row_ptr[node], end = row_ptr[node + 1];

  float acc[8] = {0.f, 0.f, 0.f, 0.f, 0.f, 0.f, 0.f, 0.f};
  const int last = end - 1;

  for (int j = beg; j < end; j += 16) {
    const int e0 = j + q, e1 = j + 4 + q, e2 = j + 8 + q, e3 = j + 12 + q;
    const int i0 = min(e0, last), i1 = min(e1, last);
    const int i2 = min(e2, last), i3 = min(e3, last);
    const int2 r0 = csr_sw[i0], r1 = csr_sw[i1], r2 = csr_sw[i2], r3 = csr_sw[i3];
    const float w0 = (e0 < end) ? __int_as_float(r0.y) : 0.0f;
    const float w1 = (e1 < end) ? __int_as_float(r1.y) : 0.0f;
    const float w2 = (e2 < end) ? __int_as_float(r2.y) : 0.0f;
    const float w3 = (e3 < end) ? __int_as_float(r3.y) : 0.0f;
    const uint4 u0 = *(const uint4*)(h_bf + (size_t)r0.x * CC + t * 8);
    const uint4 u1 = *(const uint4*)(h_bf + (size_t)r1.x * CC + t * 8);
    const uint4 u2 = *(const uint4*)(h_bf + (size_t)r2.x * CC + t * 8);
    const uint4 u3 = *(const uint4*)(h_bf + (size_t)r3.x * CC + t * 8);
    acc[0] = fmaf(bflo(u0.x), w0, acc[0]); acc[1] = fmaf(bfhi(u0.x), w0, acc[1]);
    acc[2] = fmaf(bflo(u0.y), w0, acc[2]); acc[3] = fmaf(bfhi(u0.y), w0, acc[3]);
    acc[4] = fmaf(bflo(u0.z), w0, acc[4]); acc[5] = fmaf(bfhi(u0.z), w0, acc[5]);
    acc[6] = fmaf(bflo(u0.w), w0, acc[6]); acc[7] = fmaf(bfhi(u0.w), w0, acc[7]);
    acc[0] = fmaf(bflo(u1.x), w1, acc[0]); acc[1] = fmaf(bfhi(u1.x), w1, acc[1]);
    acc[2] = fmaf(bflo(u1.y), w1, acc[2]); acc[3] = fmaf(bfhi(u1.y), w1, acc[3]);
    acc[4] = fmaf(bflo(u1.z), w1, acc[4]); acc[5] = fmaf(bfhi(u1.z), w1, acc[5]);
    acc[6] = fmaf(bflo(u1.w), w1, acc[6]); acc[7] = fmaf(bfhi(u1.w), w1, acc[7]);
    acc[0] = fmaf(bflo(u2.x), w2, acc[0]); acc[1] = fmaf(bfhi(u2.x), w2, acc[1]);
    acc[2] = fmaf(bflo(u2.y), w2, acc[2]); acc[3] = fmaf(bfhi(u2.y), w2, acc[3]);
    acc[4] = fmaf(bflo(u2.z), w2, acc[4]); acc[5] = fmaf(bfhi(u2.z), w2, acc[5]);
    acc[6] = fmaf(bflo(u2.w), w2, acc[6]); acc[7] = fmaf(bfhi(u2.w), w2, acc[7]);
    acc[0] = fmaf(bflo(u3.x), w3, acc[0]); acc[1] = fmaf(bfhi(u3.x), w3, acc[1]);
    acc[2] = fmaf(bflo(u3.y), w3, acc[2]); acc[3] = fmaf(bfhi(u3.y), w3, acc[3]);
    acc[4] = fmaf(bflo(u3.z), w3, acc[4]); acc[5] = fmaf(bfhi(u3.z), w3, acc[5]);
    acc[6] = fmaf(bflo(u3.w), w3, acc[6]); acc[7] = fmaf(bfhi(u3.w), w3, acc[7]);
  }

  #pragma unroll
  for (int i = 0; i < 8; ++i) {
    acc[i] += __shfl_xor(acc[i], 16, 64);
    acc[i] += __shfl_xor(acc[i], 32, 64);
  }

  if (q == 0) {
    uint4 o;
    o.x = (unsigned)f2bf(acc[0]) | ((unsigned)f2bf(acc[1]) << 16);
    o.y = (unsigned)f2bf(acc[2]) | ((unsigned)f2bf(acc[3]) << 16);
    o.z = (unsigned)f2bf(acc[4]) | ((unsigned)f2bf(acc[5]) << 16);
    o.w = (unsigned)f2bf(acc[6]) | ((unsigned)f2bf(acc[7]) << 16);
    *(uint4*)(agg_bf + (size_t)node * CC + t * 8) = o;
  }
}

// fused GRU via MFMA: h = GRU(aggP @ Wfuse, h).
// Wave handles 32 nodes (two 16-row M-tiles sharing every B-fragment);
// per col-block cb all three gates are computed, fused, blended, stored.
__global__ __launch_bounds__(256) void gru_kernel(
    const unsigned short* __restrict__ agg_bf, float* __restrict__ h,
    unsigned short* __restrict__ h_bf,
    const unsigned short* __restrict__ Wfuse_p, const unsigned short* __restrict__ Whh_p,
    const float* __restrict__ b_ih, const float* __restrict__ b_hh)
{
  const int lane = threadIdx.x & 63;
  const int wave = threadIdx.x >> 6;
  const int node0 = blockIdx.x * 128 + wave * 32;
  if (node0 >= NN) return;
  const int col16 = lane & 15, grp = lane >> 4;

  bf16x8 aA[2][4], aH[2][4];
  #pragma unroll
  for (int t = 0; t < 2; ++t) {
    const unsigned short* arow = agg_bf + (size_t)(node0 + t * 16 + col16) * CC + grp * 8;
    const unsigned short* hrow = h_bf  + (size_t)(node0 + t * 16 + col16) * CC + grp * 8;
    #pragma unroll
    for (int ks = 0; ks < 4; ++ks) {
      aA[t][ks] = *(const bf16x8*)(arow + ks * 32);
      aH[t][ks] = *(const bf16x8*)(hrow + ks * 32);
    }
  }

  const f32x4 z4 = {0.f, 0.f, 0.f, 0.f};

  #pragma unroll
  for (int cb = 0; cb < 8; ++cb) {
    f32x4 air[2] = {z4, z4}, ahr[2] = {z4, z4};
    f32x4 aiz[2] = {z4, z4}, ahz[2] = {z4, z4};
    f32x4 ain[2] = {z4, z4}, ahn[2] = {z4, z4};
    #pragma unroll
    for (int ks = 0; ks < 4; ++ks) {
      const size_t or_ = (size_t)((cb * 4 + ks) * 64 + lane) * 8;
      const size_t oz_ = (size_t)(((8 + cb) * 4 + ks) * 64 + lane) * 8;
      const size_t on_ = (size_t)(((16 + cb) * 4 + ks) * 64 + lane) * 8;
      bf16x8 bir = *(const bf16x8*)(Wfuse_p + or_);
      bf16x8 bhr = *(const bf16x8*)(Whh_p + or_);
      bf16x8 biz = *(const bf16x8*)(Wfuse_p + oz_);
      bf16x8 bhz = *(const bf16x8*)(Whh_p + oz_);
      bf16x8 bin = *(const bf16x8*)(Wfuse_p + on_);
      bf16x8 bhn = *(const bf16x8*)(Whh_p + on_);
      #pragma unroll
      for (int t = 0; t < 2; ++t) {
        air[t] = __builtin_amdgcn_mfma_f32_16x16x32_bf16(aA[t][ks], bir, air[t], 0, 0, 0);
        ahr[t] = __builtin_amdgcn_mfma_f32_16x16x32_bf16(aH[t][ks], bhr, ahr[t], 0, 0, 0);
        aiz[t] = __builtin_amdgcn_mfma_f32_16x16x32_bf16(aA[t][ks], biz, aiz[t], 0, 0, 0);
        ahz[t] = __builtin_amdgcn_mfma_f32_16x16x32_bf16(aH[t][ks], bhz, ahz[t], 0, 0, 0);
        ain[t] = __builtin_amdgcn_mfma_f32_16x16x32_bf16(aA[t][ks], bin, ain[t], 0, 0, 0);
        ahn[t] = __builtin_amdgcn_mfma_f32_16x16x32_bf16(aH[t][ks], bhn, ahn[t], 0, 0, 0);
      }
    }
    const int o = cb * 16 + col16;
    const float bir_ = b_ih[o],       bhr_ = b_hh[o];
    const float biz_ = b_ih[128 + o], bhz_ = b_hh[128 + o];
    const float bin_ = b_ih[256 + o], bhn_ = b_hh[256 + o];
    #pragma unroll
    for (int t = 0; t < 2; ++t) {
      #pragma unroll
      for (int r = 0; r < 4; ++r) {
        float rr = sigmoidf_(air[t][r] + ahr[t][r] + bir_ + bhr_);
        float zz = sigmoidf_(aiz[t][r] + ahz[t][r] + biz_ + bhz_);
        float nn = tanhf_(ain[t][r] + bin_ + rr * (ahn[t][r] + bhn_));
        size_t idx = (size_t)(node0 + t * 16 + grp * 4 + r) * CC + o;
        float hn = (1.0f - zz) * nn + zz * h[idx];
        h[idx] = hn;
        h_bf[idx] = f2bf(hn);
      }
    }
  }
}

// out[batch[n]] += h[n] . W_prop + b_prop   (wave per node)
__global__ __launch_bounds__(256) void prop_kernel(
    const float* __restrict__ h, const int* __restrict__ batch,
    const float* __restrict__ Wp, const float* __restrict__ bp,
    float* __restrict__ out)
{
  const int lane = threadIdx.x & 63;
  const int wid = (blockIdx.x * blockDim.x + threadIdx.x) >> 6;
  const int nw = (gridDim.x * blockDim.x) >> 6;
  for (int node = wid; node < NN; node += nw) {
    float v = h[(size_t)node * CC + lane] * Wp[lane]
            + h[(size_t)node * CC + 64 + lane] * Wp[64 + lane];
    #pragma unroll
    for (int off = 32; off > 0; off >>= 1) v += __shfl_down(v, off, 64);
    if (lane == 0) atomicAdd(&out[batch[node]], v + bp[0]);
  }
}

extern "C" void kernel_launch(void* const* d_in, const int* in_sizes, int n_in,
                              void* d_out, int out_size, void* d_ws, size_t ws_size,
                              hipStream_t stream)
{
  const float* x      = (const float*)d_in[0];
  const int*   eidx   = (const int*)d_in[1];
  const float* ew     = (const float*)d_in[2];
  const int*   batch  = (const int*)d_in[3];
  const float* W_emb  = (const float*)d_in[4];
  const float* b_emb  = (const float*)d_in[5];
  const float* W      = (const float*)d_in[6];
  const float* W_ih   = (const float*)d_in[7];
  const float* W_hh   = (const float*)d_in[8];
  const float* b_ih   = (const float*)d_in[9];
  const float* b_hh   = (const float*)d_in[10];
  const float* W_prop = (const float*)d_in[11];
  const float* b_prop = (const float*)d_in[12];
  float* out = (float*)d_out;

  // workspace layout (~116 MB)
  char* p = (char*)d_ws;
  float* h              = (float*)p;          p += (size_t)NN * CC * sizeof(float);  // 51.2 MB
  unsigned short* h_bf  = (unsigned short*)p; p += (size_t)NN * CC * sizeof(short);  // 25.6 MB
  unsigned short* agg   = (unsigned short*)p; p += (size_t)NN * CC * sizeof(short);  // 25.6 MB
  int2* csr_sw          = (int2*)p;           p += (size_t)EE * sizeof(int2);        // 12.8 MB
  unsigned short* Wfuse_p = (unsigned short*)p; p += (size_t)LL * 49152 * sizeof(short);
  unsigned short* Whh_p = (unsigned short*)p; p += (size_t)49152 * sizeof(short);
  int* deg     = (int*)p;                     p += (size_t)(NN + 256) * sizeof(int);
  int* row_ptr = (int*)p;                     p += (size_t)(NN + 256) * sizeof(int);
  int* cursor  = (int*)p;                     p += (size_t)(NN + 256) * sizeof(int);
  int* bsum    = (int*)p;                     p += 1024 * sizeof(int);

  const int NB_SCAN = (NN + 1023) / 1024;   // 98
  const int EB = (EE + 255) / 256;          // 6250
  const int MB2 = (NN + 127) / 128;         // 782 (gru: 128 nodes/block)

  // ---- weight prepack (once per call) ----
  pack_kernel<<<192, 256, 0, stream>>>(W_hh, Whh_p);
  for (int l = 0; l < LL; ++l)
    fuse_pack_kernel<<<192, 256, 0, stream>>>(W + (size_t)l * CC * CC, W_ih,
                                              Wfuse_p + (size_t)l * 49152);

  // ---- CSR build (direct scatter; 100K cursors -> no atomic contention) ----
  hipMemsetAsync(deg, 0, (size_t)NN * sizeof(int), stream);
  hist_kernel<<<EB, 256, 0, stream>>>(eidx, deg);
  scan1_kernel<<<NB_SCAN, 256, 0, stream>>>(deg, bsum);
  scan2_kernel<<<1, 64, 0, stream>>>(bsum, NB_SCAN);
  scan3_kernel<<<NB_SCAN, 256, 0, stream>>>(deg, bsum, row_ptr, cursor);
  fill_kernel<<<EB, 256, 0, stream>>>(eidx, ew, cursor, csr_sw);

  // ---- main pipeline ----
  embed_kernel<<<NN, 128, 0, stream>>>(x, W_emb, b_emb, h, h_bf);

  for (int l = 0; l < LL; ++l) {
    aggregate_kernel<<<(NN + 3) / 4, 256, 0, stream>>>(h_bf, row_ptr, csr_sw, agg);
    gru_kernel<<<MB2, 256, 0, stream>>>(agg, h, h_bf,
                                        Wfuse_p + (size_t)l * 49152, Whh_p, b_ih, b_hh);
  }

  hipMemsetAsync(d_out, 0, (size_t)GG * sizeof(float), stream);
  prop_kernel<<<2048, 256, 0, stream>>>(h, batch, W_prop, b_prop, out);
}

// Round 8
// 914.547 us; speedup vs baseline: 1.3571x; 1.0359x over previous
//
#include <hip/hip_runtime.h>

#define NN 100000
#define CC 128
#define EE 1600000
#define GG 1024
#define LL 5
#define NBUCKET 12500        // NN/8 exactly; 8 nodes per bucket

typedef __attribute__((ext_vector_type(8))) short bf16x8;
typedef __attribute__((ext_vector_type(4))) float f32x4;

__device__ __forceinline__ float sigmoidf_(float x) { return 1.0f / (1.0f + __expf(-x)); }
__device__ __forceinline__ float tanhf_(float x) {
  float xx = fminf(15.0f, fmaxf(-15.0f, x));
  float t = __expf(-2.0f * xx);
  return (1.0f - t) / (1.0f + t);
}
// f32 -> bf16 round-to-nearest-even
__device__ __forceinline__ unsigned short f2bf(float x) {
  unsigned int u = __float_as_uint(x);
  return (unsigned short)((u + 0x7fffu + ((u >> 16) & 1u)) >> 16);
}
__device__ __forceinline__ float bflo(unsigned int u) { return __uint_as_float(u << 16); }
__device__ __forceinline__ float bfhi(unsigned int u) { return __uint_as_float(u & 0xffff0000u); }
__device__ __forceinline__ float bf2f(unsigned short v) { return __uint_as_float((unsigned)v << 16); }

// ---------------- weight prepack ----------------
// Packed B-fragment layout: element (k, c) at t = ((cb*4+ks)*64 + l)*8 + i
// with k = ks*32 + 8*(l>>4) + i, c = cb*16 + (l&15).

// Whh: B[k][c] = W_hh[c][k]  (gh = h @ W_hh^T)
__global__ __launch_bounds__(256) void pack_kernel(
    const float* __restrict__ src, unsigned short* __restrict__ dst)
{
  int t = blockIdx.x * 256 + threadIdx.x;           // 24*4*64*8 = 49152
  int i = t & 7, l = (t >> 3) & 63, q = t >> 9;
  int ks = q & 3, cb = q >> 2;
  int k = ks * 32 + 8 * (l >> 4) + i;
  int c = cb * 16 + (l & 15);
  dst[t] = f2bf(src[(size_t)c * CC + k]);
}

// Wfuse_l[k][c] = sum_j W_l[k][j] * W_ih[c][j]   (gi = aggP @ Wfuse)
__global__ __launch_bounds__(256) void fuse_pack_kernel(
    const float* __restrict__ Wl, const float* __restrict__ W_ih,
    unsigned short* __restrict__ dst)
{
  int t = blockIdx.x * 256 + threadIdx.x;           // 49152 per layer
  int i = t & 7, l = (t >> 3) & 63, q = t >> 9;
  int ks = q & 3, cb = q >> 2;
  int k = ks * 32 + 8 * (l >> 4) + i;
  int c = cb * 16 + (l & 15);
  const float* wl = Wl + (size_t)k * CC;
  const float* wi = W_ih + (size_t)c * CC;
  float acc = 0.f;
  #pragma unroll 8
  for (int j = 0; j < CC; ++j) acc = fmaf(wl[j], wi[j], acc);
  dst[t] = f2bf(acc);
}

// ---------------- CSR build (once per call) ----------------

__global__ __launch_bounds__(256) void hist_kernel(const int* __restrict__ eidx,
                                                   int* __restrict__ deg)
{
  int e = blockIdx.x * blockDim.x + threadIdx.x;
  if (e < EE) atomicAdd(&deg[eidx[EE + e]], 1);
}

__global__ __launch_bounds__(256) void scan1_kernel(const int* __restrict__ deg,
                                                    int* __restrict__ bsum)
{
  __shared__ int red[4];
  int base = blockIdx.x * 1024 + threadIdx.x * 4;
  int s = 0;
  #pragma unroll
  for (int i = 0; i < 4; ++i) { int idx = base + i; if (idx < NN) s += deg[idx]; }
  #pragma unroll
  for (int off = 32; off; off >>= 1) s += __shfl_down(s, off, 64);
  if ((threadIdx.x & 63) == 0) red[threadIdx.x >> 6] = s;
  __syncthreads();
  if (threadIdx.x == 0) bsum[blockIdx.x] = red[0] + red[1] + red[2] + red[3];
}

__global__ void scan2_kernel(int* __restrict__ bsum, int nb)
{
  if (threadIdx.x == 0 && blockIdx.x == 0) {
    int acc = 0;
    for (int i = 0; i < nb; ++i) { int v = bsum[i]; bsum[i] = acc; acc += v; }
  }
}

__global__ __launch_bounds__(256) void scan3_kernel(const int* __restrict__ deg,
                                                    const int* __restrict__ bsum,
                                                    int* __restrict__ row_ptr)
{
  __shared__ int ts[256];
  const int tid = threadIdx.x;
  const int base = blockIdx.x * 1024 + tid * 4;
  int v[4]; int s = 0;
  #pragma unroll
  for (int i = 0; i < 4; ++i) { int idx = base + i; v[i] = (idx < NN) ? deg[idx] : 0; s += v[i]; }
  ts[tid] = s; __syncthreads();
  for (int off = 1; off < 256; off <<= 1) {
    int t = (tid >= off) ? ts[tid - off] : 0;
    __syncthreads();
    ts[tid] += t;
    __syncthreads();
  }
  int excl = bsum[blockIdx.x] + ts[tid] - s;
  #pragma unroll
  for (int i = 0; i < 4; ++i) {
    int idx = base + i;
    if (idx < NN) { row_ptr[idx] = excl; excl += v[i]; }
  }
  if (blockIdx.x == 0 && tid == 0) row_ptr[NN] = EE;
}

// bucket cursors: bucket b owns nodes [8b, 8b+8) -> CSR span starts at row_ptr[8b]
__global__ void bcur_init_kernel(const int* __restrict__ row_ptr, int* __restrict__ bcur)
{
  int b = blockIdx.x * blockDim.x + threadIdx.x;
  if (b < NBUCKET) bcur[b] = row_ptr[b * 8];
}

// phase 1: append edges into dst-bucket span. 12500 cursors -> ~128 atomics each
// (R6 calibration: 330cyc/atomic serialization => ~20us); dense appends ~1x write amp.
__global__ __launch_bounds__(256) void fill_bucket_kernel(
    const int* __restrict__ eidx, const float* __restrict__ ew,
    int* __restrict__ bcur, int2* __restrict__ bucket)
{
  int e = blockIdx.x * blockDim.x + threadIdx.x;
  if (e < EE) {
    int d = eidx[EE + e];
    int p = atomicAdd(&bcur[d >> 3], 1);
    bucket[p] = make_int2(eidx[e] | ((d & 7) << 17), __float_as_int(ew[e]));
  }
}

// phase 2: one block per bucket; 8 LDS cursors; scatter confined to ~1KB L2 span
__global__ __launch_bounds__(128) void fill_csr_kernel(
    const int* __restrict__ row_ptr, const int2* __restrict__ bucket,
    int2* __restrict__ csr_sw)
{
  __shared__ int cur[8];
  const int b = blockIdx.x;
  const int tid = threadIdx.x;
  if (tid < 8) cur[tid] = row_ptr[b * 8 + tid];
  __syncthreads();
  const int start = row_ptr[b * 8];
  const int stop  = row_ptr[b * 8 + 8];
  for (int j = start + tid; j < stop; j += 128) {
    int2 r = bucket[j];
    unsigned u = (unsigned)r.x;
    int p = atomicAdd(&cur[u >> 17], 1);
    csr_sw[p] = make_int2((int)(u & 0x1FFFFu), r.y);
  }
}

// ---------------- main pipeline ----------------

// h0 = x @ W_emb + b_emb; bf16 state only
__global__ __launch_bounds__(128) void embed_kernel(
    const float* __restrict__ x, const float* __restrict__ W_emb,
    const float* __restrict__ b_emb, unsigned short* __restrict__ h_bf)
{
  const int node = blockIdx.x;
  const int c = threadIdx.x;
  float acc = b_emb[c];
  #pragma unroll
  for (int k = 0; k < 32; ++k)
    acc = fmaf(x[node * 32 + k], W_emb[k * CC + c], acc);
  h_bf[(size_t)node * CC + c] = f2bf(acc);
}

// agg_bf[n] = bf16( sum_{e:dst=n} h_bf[src_e] * w_e ) — CSR gather.
// 4 quarters x 16 lanes; 16 edges in flight (typical node = ONE iteration).
__global__ __launch_bounds__(256) void aggregate_kernel(
    const unsigned short* __restrict__ h_bf, const int* __restrict__ row_ptr,
    const int2* __restrict__ csr_sw, unsigned short* __restrict__ agg_bf)
{
  const int lane = threadIdx.x & 63;
  const int node = (blockIdx.x * blockDim.x + threadIdx.x) >> 6;
  if (node >= NN) return;
  const int q = lane >> 4;          // quarter 0..3
  const int t = lane & 15;          // lane within quarter
  const int beg = row_ptr[node], end = row_ptr[node + 1];

  float acc[8] = {0.f, 0.f, 0.f, 0.f, 0.f, 0.f, 0.f, 0.f};
  const int last = end - 1;

  for (int j = beg; j < end; j += 16) {
    const int e0 = j + q, e1 = j + 4 + q, e2 = j + 8 + q, e3 = j + 12 + q;
    const int i0 = min(e0, last), i1 = min(e1, last);
    const int i2 = min(e2, last), i3 = min(e3, last);
    const int2 r0 = csr_sw[i0], r1 = csr_sw[i1], r2 = csr_sw[i2], r3 = csr_sw[i3];
    const float w0 = (e0 < end) ? __int_as_float(r0.y) : 0.0f;
    const float w1 = (e1 < end) ? __int_as_float(r1.y) : 0.0f;
    const float w2 = (e2 < end) ? __int_as_float(r2.y) : 0.0f;
    const float w3 = (e3 < end) ? __int_as_float(r3.y) : 0.0f;
    const uint4 u0 = *(const uint4*)(h_bf + (size_t)r0.x * CC + t * 8);
    const uint4 u1 = *(const uint4*)(h_bf + (size_t)r1.x * CC + t * 8);
    const uint4 u2 = *(const uint4*)(h_bf + (size_t)r2.x * CC + t * 8);
    const uint4 u3 = *(const uint4*)(h_bf + (size_t)r3.x * CC + t * 8);
    acc[0] = fmaf(bflo(u0.x), w0, acc[0]); acc[1] = fmaf(bfhi(u0.x), w0, acc[1]);
    acc[2] = fmaf(bflo(u0.y), w0, acc[2]); acc[3] = fmaf(bfhi(u0.y), w0, acc[3]);
    acc[4] = fmaf(bflo(u0.z), w0, acc[4]); acc[5] = fmaf(bfhi(u0.z), w0, acc[5]);
    acc[6] = fmaf(bflo(u0.w), w0, acc[6]); acc[7] = fmaf(bfhi(u0.w), w0, acc[7]);
    acc[0] = fmaf(bflo(u1.x), w1, acc[0]); acc[1] = fmaf(bfhi(u1.x), w1, acc[1]);
    acc[2] = fmaf(bflo(u1.y), w1, acc[2]); acc[3] = fmaf(bfhi(u1.y), w1, acc[3]);
    acc[4] = fmaf(bflo(u1.z), w1, acc[4]); acc[5] = fmaf(bfhi(u1.z), w1, acc[5]);
    acc[6] = fmaf(bflo(u1.w), w1, acc[6]); acc[7] = fmaf(bfhi(u1.w), w1, acc[7]);
    acc[0] = fmaf(bflo(u2.x), w2, acc[0]); acc[1] = fmaf(bfhi(u2.x), w2, acc[1]);
    acc[2] = fmaf(bflo(u2.y), w2, acc[2]); acc[3] = fmaf(bfhi(u2.y), w2, acc[3]);
    acc[4] = fmaf(bflo(u2.z), w2, acc[4]); acc[5] = fmaf(bfhi(u2.z), w2, acc[5]);
    acc[6] = fmaf(bflo(u2.w), w2, acc[6]); acc[7] = fmaf(bfhi(u2.w), w2, acc[7]);
    acc[0] = fmaf(bflo(u3.x), w3, acc[0]); acc[1] = fmaf(bfhi(u3.x), w3, acc[1]);
    acc[2] = fmaf(bflo(u3.y), w3, acc[2]); acc[3] = fmaf(bfhi(u3.y), w3, acc[3]);
    acc[4] = fmaf(bflo(u3.z), w3, acc[4]); acc[5] = fmaf(bfhi(u3.z), w3, acc[5]);
    acc[6] = fmaf(bflo(u3.w), w3, acc[6]); acc[7] = fmaf(bfhi(u3.w), w3, acc[7]);
  }

  #pragma unroll
  for (int i = 0; i < 8; ++i) {
    acc[i] += __shfl_xor(acc[i], 16, 64);
    acc[i] += __shfl_xor(acc[i], 32, 64);
  }

  if (q == 0) {
    uint4 o;
    o.x = (unsigned)f2bf(acc[0]) | ((unsigned)f2bf(acc[1]) << 16);
    o.y = (unsigned)f2bf(acc[2]) | ((unsigned)f2bf(acc[3]) << 16);
    o.z = (unsigned)f2bf(acc[4]) | ((unsigned)f2bf(acc[5]) << 16);
    o.w = (unsigned)f2bf(acc[6]) | ((unsigned)f2bf(acc[7]) << 16);
    *(uint4*)(agg_bf + (size_t)node * CC + t * 8) = o;
  }
}

// fused GRU via MFMA: h_bf = GRU(aggP @ Wfuse, h_bf). bf16 state only.
// Wave handles 32 nodes (two 16-row M-tiles sharing every B-fragment).
__global__ __launch_bounds__(256) void gru_kernel(
    const unsigned short* __restrict__ agg_bf, unsigned short* __restrict__ h_bf,
    const unsigned short* __restrict__ Wfuse_p, const unsigned short* __restrict__ Whh_p,
    const float* __restrict__ b_ih, const float* __restrict__ b_hh)
{
  const int lane = threadIdx.x & 63;
  const int wave = threadIdx.x >> 6;
  const int node0 = blockIdx.x * 128 + wave * 32;
  if (node0 >= NN) return;
  const int col16 = lane & 15, grp = lane >> 4;

  bf16x8 aA[2][4], aH[2][4];
  #pragma unroll
  for (int t = 0; t < 2; ++t) {
    const unsigned short* arow = agg_bf + (size_t)(node0 + t * 16 + col16) * CC + grp * 8;
    const unsigned short* hrow = h_bf  + (size_t)(node0 + t * 16 + col16) * CC + grp * 8;
    #pragma unroll
    for (int ks = 0; ks < 4; ++ks) {
      aA[t][ks] = *(const bf16x8*)(arow + ks * 32);
      aH[t][ks] = *(const bf16x8*)(hrow + ks * 32);
    }
  }

  const f32x4 z4 = {0.f, 0.f, 0.f, 0.f};

  #pragma unroll
  for (int cb = 0; cb < 8; ++cb) {
    f32x4 air[2] = {z4, z4}, ahr[2] = {z4, z4};
    f32x4 aiz[2] = {z4, z4}, ahz[2] = {z4, z4};
    f32x4 ain[2] = {z4, z4}, ahn[2] = {z4, z4};
    #pragma unroll
    for (int ks = 0; ks < 4; ++ks) {
      const size_t or_ = (size_t)((cb * 4 + ks) * 64 + lane) * 8;
      const size_t oz_ = (size_t)(((8 + cb) * 4 + ks) * 64 + lane) * 8;
      const size_t on_ = (size_t)(((16 + cb) * 4 + ks) * 64 + lane) * 8;
      bf16x8 bir = *(const bf16x8*)(Wfuse_p + or_);
      bf16x8 bhr = *(const bf16x8*)(Whh_p + or_);
      bf16x8 biz = *(const bf16x8*)(Wfuse_p + oz_);
      bf16x8 bhz = *(const bf16x8*)(Whh_p + oz_);
      bf16x8 bin = *(const bf16x8*)(Wfuse_p + on_);
      bf16x8 bhn = *(const bf16x8*)(Whh_p + on_);
      #pragma unroll
      for (int t = 0; t < 2; ++t) {
        air[t] = __builtin_amdgcn_mfma_f32_16x16x32_bf16(aA[t][ks], bir, air[t], 0, 0, 0);
        ahr[t] = __builtin_amdgcn_mfma_f32_16x16x32_bf16(aH[t][ks], bhr, ahr[t], 0, 0, 0);
        aiz[t] = __builtin_amdgcn_mfma_f32_16x16x32_bf16(aA[t][ks], biz, aiz[t], 0, 0, 0);
        ahz[t] = __builtin_amdgcn_mfma_f32_16x16x32_bf16(aH[t][ks], bhz, ahz[t], 0, 0, 0);
        ain[t] = __builtin_amdgcn_mfma_f32_16x16x32_bf16(aA[t][ks], bin, ain[t], 0, 0, 0);
        ahn[t] = __builtin_amdgcn_mfma_f32_16x16x32_bf16(aH[t][ks], bhn, ahn[t], 0, 0, 0);
      }
    }
    const int o = cb * 16 + col16;
    const float bir_ = b_ih[o],       bhr_ = b_hh[o];
    const float biz_ = b_ih[128 + o], bhz_ = b_hh[128 + o];
    const float bin_ = b_ih[256 + o], bhn_ = b_hh[256 + o];
    #pragma unroll
    for (int t = 0; t < 2; ++t) {
      #pragma unroll
      for (int r = 0; r < 4; ++r) {
        float rr = sigmoidf_(air[t][r] + ahr[t][r] + bir_ + bhr_);
        float zz = sigmoidf_(aiz[t][r] + ahz[t][r] + biz_ + bhz_);
        float nn = tanhf_(ain[t][r] + bin_ + rr * (ahn[t][r] + bhn_));
        size_t idx = (size_t)(node0 + t * 16 + grp * 4 + r) * CC + o;
        float ho = bf2f(h_bf[idx]);
        h_bf[idx] = f2bf((1.0f - zz) * nn + zz * ho);
      }
    }
  }
}

// out[batch[n]] += h[n] . W_prop + b_prop   (wave per node; bf16 h)
__global__ __launch_bounds__(256) void prop_kernel(
    const unsigned short* __restrict__ h_bf, const int* __restrict__ batch,
    const float* __restrict__ Wp, const float* __restrict__ bp,
    float* __restrict__ out)
{
  const int lane = threadIdx.x & 63;
  const int wid = (blockIdx.x * blockDim.x + threadIdx.x) >> 6;
  const int nw = (gridDim.x * blockDim.x) >> 6;
  for (int node = wid; node < NN; node += nw) {
    unsigned int u = *(const unsigned int*)(h_bf + (size_t)node * CC + 2 * lane);
    float v = bflo(u) * Wp[2 * lane] + bfhi(u) * Wp[2 * lane + 1];
    #pragma unroll
    for (int off = 32; off > 0; off >>= 1) v += __shfl_down(v, off, 64);
    if (lane == 0) atomicAdd(&out[batch[node]], v + bp[0]);
  }
}

extern "C" void kernel_launch(void* const* d_in, const int* in_sizes, int n_in,
                              void* d_out, int out_size, void* d_ws, size_t ws_size,
                              hipStream_t stream)
{
  const float* x      = (const float*)d_in[0];
  const int*   eidx   = (const int*)d_in[1];
  const float* ew     = (const float*)d_in[2];
  const int*   batch  = (const int*)d_in[3];
  const float* W_emb  = (const float*)d_in[4];
  const float* b_emb  = (const float*)d_in[5];
  const float* W      = (const float*)d_in[6];
  const float* W_ih   = (const float*)d_in[7];
  const float* W_hh   = (const float*)d_in[8];
  const float* b_ih   = (const float*)d_in[9];
  const float* b_hh   = (const float*)d_in[10];
  const float* W_prop = (const float*)d_in[11];
  const float* b_prop = (const float*)d_in[12];
  float* out = (float*)d_out;

  // workspace layout (~78 MB)
  char* p = (char*)d_ws;
  unsigned short* h_bf  = (unsigned short*)p; p += (size_t)NN * CC * sizeof(short);  // 25.6 MB
  unsigned short* agg   = (unsigned short*)p; p += (size_t)NN * CC * sizeof(short);  // 25.6 MB
  int2* csr_sw          = (int2*)p;           p += (size_t)EE * sizeof(int2);        // 12.8 MB
  int2* bucket          = (int2*)p;           p += (size_t)EE * sizeof(int2);        // 12.8 MB
  unsigned short* Wfuse_p = (unsigned short*)p; p += (size_t)LL * 49152 * sizeof(short);
  unsigned short* Whh_p = (unsigned short*)p; p += (size_t)49152 * sizeof(short);
  int* deg     = (int*)p;                     p += (size_t)(NN + 256) * sizeof(int);
  int* row_ptr = (int*)p;                     p += (size_t)(NN + 256) * sizeof(int);
  int* bcur    = (int*)p;                     p += (size_t)(NBUCKET + 64) * sizeof(int);
  int* bsum    = (int*)p;                     p += 1024 * sizeof(int);

  const int NB_SCAN = (NN + 1023) / 1024;   // 98
  const int EB = (EE + 255) / 256;          // 6250
  const int MB2 = (NN + 127) / 128;         // 782 (gru: 128 nodes/block)

  // ---- weight prepack (once per call) ----
  pack_kernel<<<192, 256, 0, stream>>>(W_hh, Whh_p);
  for (int l = 0; l < LL; ++l)
    fuse_pack_kernel<<<192, 256, 0, stream>>>(W + (size_t)l * CC * CC, W_ih,
                                              Wfuse_p + (size_t)l * 49152);

  // ---- CSR build: hist -> scan -> 12500-bucket scatter -> per-bucket CSR ----
  hipMemsetAsync(deg, 0, (size_t)NN * sizeof(int), stream);
  hist_kernel<<<EB, 256, 0, stream>>>(eidx, deg);
  scan1_kernel<<<NB_SCAN, 256, 0, stream>>>(deg, bsum);
  scan2_kernel<<<1, 64, 0, stream>>>(bsum, NB_SCAN);
  scan3_kernel<<<NB_SCAN, 256, 0, stream>>>(deg, bsum, row_ptr);
  bcur_init_kernel<<<(NBUCKET + 255) / 256, 256, 0, stream>>>(row_ptr, bcur);
  fill_bucket_kernel<<<EB, 256, 0, stream>>>(eidx, ew, bcur, bucket);
  fill_csr_kernel<<<NBUCKET, 128, 0, stream>>>(row_ptr, bucket, csr_sw);

  // ---- main pipeline ----
  embed_kernel<<<NN, 128, 0, stream>>>(x, W_emb, b_emb, h_bf);

  for (int l = 0; l < LL; ++l) {
    aggregate_kernel<<<(NN + 3) / 4, 256, 0, stream>>>(h_bf, row_ptr, csr_sw, agg);
    gru_kernel<<<MB2, 256, 0, stream>>>(agg, h_bf,
                                        Wfuse_p + (size_t)l * 49152, Whh_p, b_ih, b_hh);
  }

  hipMemsetAsync(d_out, 0, (size_t)GG * sizeof(float), stream);
  prop_kernel<<<2048, 256, 0, stream>>>(h_bf, batch, W_prop, b_prop, out);
}